// Round 2
// baseline (1543.329 us; speedup 1.0000x reference)
//
#include <hip/hip_runtime.h>

// Custom LSTM scan.  B=64, L=512, P=64, A=16, D=512, F=80.
//   h_t = h_{t-1} + tanh(x_t W_ci + b_ci) * sigmoid(h_{t-1} R_ig + b_ig)
//
// R7: output-dim split of the per-row matvec across NQ=4 WGs (256 WGs =
// 1/CU).  Each WG owns 128 outputs x full K=512 -> per-thread R is 16
// uint4 = 64 VGPRs, fully resident at the 128-VGPR budget.  Per-step
// cross-WG h exchange (1KB) via L3: relaxed agent-scope f16-pair stores +
// per-WG flag posted after the barrier's vmcnt drain; partner lanes read
// their h-slice with global_load_dwordx4 sc0 sc1 (cross-XCD coherent).
// R7 fix vs R6: hp (own-quarter h pairs in LDS) is DOUBLE-BUFFERED by step
// parity.  R6 had a single buffer with one barrier -> a fast wave's write
// of h_t raced a slow wave's read of h_{t-1} (intra-WG, compounding over
// 512 steps -> absmax 0.95).  Parity buffers restore race-freedom at one
// barrier/step.  Flag protocol unchanged (proven write-after-read safe:
// step-t hbuf write happens after the step-t flag-wait, which implies
// partners finished their step-(t-1) reads of that parity buffer).

#define B_  64
#define L_  512
#define P_  64
#define A_  16
#define D_  512
#define F_  80
#define CI_R 8
#define NQ  4

#define CI_BYTES   ((size_t)B_ * L_ * D_ * 2)       // 33,554,432
#define RP_BYTES   ((size_t)D_ * D_ * 2)            // 524,288
#define HBUF_BYTES ((size_t)(2 * B_ * NQ * 64) * 4) // 131,072
#define FLAG_UINTS (B_ * 16)                        // 4 KB, 64B/row padding

typedef _Float16 half2_t __attribute__((ext_vector_type(2)));
typedef unsigned int uintx4 __attribute__((ext_vector_type(4)));

__device__ __forceinline__ float dot2(unsigned int r, unsigned int h, float acc) {
    return __builtin_amdgcn_fdot2(__builtin_bit_cast(half2_t, h),
                                  __builtin_bit_cast(half2_t, r), acc, false);
}
__device__ __forceinline__ float dot4u(uintx4 r, uintx4 h, float acc) {
    acc = dot2(r.x, h.x, acc);
    acc = dot2(r.y, h.y, acc);
    acc = dot2(r.z, h.z, acc);
    acc = dot2(r.w, h.w, acc);
    return acc;
}
template<int CTRL>
__device__ __forceinline__ float dpp_mov(float v) {
    return __builtin_bit_cast(float, __builtin_amdgcn_update_dpp(
        0, __builtin_bit_cast(int, v), CTRL, 0xF, 0xF, true));
}
// DPP ctrls: 0xB1=xor1, 0x4E=xor2, 0x141=row_half_mirror(xor7),
// 0x140=row_mirror(xor15), 0x142=row_bcast15, 0x143=row_bcast31.

// Pack R_ig fp32[k][d] -> f16-pair uint chunks, layout [Q][m][tid_s][q]:
// WG quarter Q, thread tid_s (w=tid_s>>6, l=tid_s&63, r=l>>3, g=l&7),
// chunk m=j*8+c holds pairs for output d = Q*128 + (w*8+r)*2 + j at
// k = g*64 + c*8 + 2q (+1).  Also zeroes flags and out each launch.
__global__ __launch_bounds__(256) void prep_kernel(const float* __restrict__ R,
        unsigned int* __restrict__ Rp, unsigned int* __restrict__ flags,
        float* __restrict__ out) {
    int id = blockIdx.x * 256 + threadIdx.x;          // 131072 uints
    int q = id & 3;
    int U = id >> 2;
    int tid_s = U & 511;
    int m  = (U >> 9) & 15;
    int Qq = U >> 13;
    int w = tid_s >> 6, l = tid_s & 63, r = l >> 3, g = l & 7;
    int j = m >> 3, c = m & 7;
    int d  = Qq * 128 + (w * 8 + r) * 2 + j;
    int k0 = g * 64 + c * 8 + 2 * q;
    half2_t v;
    v.x = (_Float16)R[k0 * D_ + d];
    v.y = (_Float16)R[(k0 + 1) * D_ + d];
    Rp[id] = __builtin_bit_cast(unsigned int, v);
    if (id < FLAG_UINTS) flags[id] = 0u;
    if (id < B_ * L_) out[id] = 0.f;
}

// ci = tanh(x @ W_ci + b_ci), stored f16.  One block does CI_R (b,l) rows.
__global__ __launch_bounds__(256) void ci_kernel(const float* __restrict__ obs,
                                                 const float* __restrict__ act,
                                                 const float* __restrict__ W,
                                                 const float* __restrict__ bci,
                                                 unsigned short* __restrict__ ci) {
    __shared__ float xs[CI_R][F_];
    int row0 = blockIdx.x * CI_R;
    int tid = threadIdx.x;
    for (int idx = tid; idx < CI_R * F_; idx += 256) {
        int r = idx / F_, f = idx % F_;
        float v = (f < P_) ? obs[(size_t)(row0 + r) * P_ + f]
                           : act[(size_t)(row0 + r) * A_ + (f - P_)];
        xs[r][f] = v;
    }
    __syncthreads();
    int d0 = tid, d1 = tid + 256;
    float a0[CI_R], a1[CI_R];
    #pragma unroll
    for (int r = 0; r < CI_R; ++r) { a0[r] = 0.f; a1[r] = 0.f; }
    for (int f = 0; f < F_; ++f) {
        float w0 = W[f * D_ + d0];
        float w1 = W[f * D_ + d1];
        #pragma unroll
        for (int r = 0; r < CI_R; ++r) {
            float xv = xs[r][f];
            a0[r] += xv * w0;
            a1[r] += xv * w1;
        }
    }
    float b0 = bci[d0], b1 = bci[d1];
    #pragma unroll
    for (int r = 0; r < CI_R; ++r) {
        float z0 = a0[r] + b0, z1 = a1[r] + b1;
        float e0 = __expf(-2.f * __builtin_fabsf(z0));
        float e1 = __expf(-2.f * __builtin_fabsf(z1));
        float m0 = (1.f - e0) * __builtin_amdgcn_rcpf(1.f + e0);
        float m1 = (1.f - e1) * __builtin_amdgcn_rcpf(1.f + e1);
        float t0 = z0 < 0.f ? -m0 : m0;
        float t1 = z1 < 0.f ? -m1 : m1;
        ci[(size_t)(row0 + r) * D_ + d0] = __builtin_bit_cast(unsigned short, (_Float16)t0);
        ci[(size_t)(row0 + r) * D_ + d1] = __builtin_bit_cast(unsigned short, (_Float16)t1);
    }
}

// Serial scan, 4 WGs per batch row (output split).  WG (row, Q) owns
// d in [Q*128, Q*128+128).  Thread (w=tid>>6, l=tid&63, r=l>>3, g=l&7)
// computes partials over k in [g*64, g*64+64) for 2 outputs
// d = Q*128 + (w*8+r)*2 + {0,1}; 8-lane DPP full-reduce, lane owns j=g&1.
// All 16 R chunks live in VGPRs.  h slice source: own k-quarter (g>>1==Q)
// from parity-buffered LDS hp2 (swizzled f16 pairs); other quarters via
// coherent global loads from partner hbuf (ping-pong by parity), flag-gated.
__global__ __launch_bounds__(512, 2)
__attribute__((amdgpu_waves_per_eu(2, 2)))
void scan_kernel(const unsigned int* __restrict__ Rp,
                 const unsigned short* __restrict__ ci,
                 const float* __restrict__ b_ig, const float* __restrict__ W_out,
                 const float* __restrict__ b_out, float* __restrict__ out,
                 unsigned int* __restrict__ hbuf, unsigned int* __restrict__ flags)
{
    const int tid = threadIdx.x;
    const int bid = blockIdx.x;
    const int row = bid & 63;          // bid%8 == row%8 -> row's 4 WGs same XCD
    const int Q   = bid >> 6;
    const int w = tid >> 6;
    const int l = tid & 63;
    const int r = l >> 3;
    const int g = l & 7;
    const int pq = g >> 1;             // k-quarter this lane's slice lives in
    const bool own = (pq == Q);

    __shared__ __align__(16) unsigned int hp2[2][256];  // own-quarter h pairs, parity
    __shared__ float red[2][8];                         // po partials, parity

    // all 16 R chunks pinned in VGPRs (64 regs)
    const uintx4* tb = (const uintx4*)Rp + (size_t)Q * 8192 + tid;
    uintx4 rr[16];
    #pragma unroll
    for (int m = 0; m < 16; ++m) rr[m] = tb[m * 512];
    #pragma unroll
    for (int m = 0; m < 16; ++m) asm volatile("" : "+v"(rr[m]));

    const int dloc = (w * 8 + r) * 2 + (g & 1);
    const int down = Q * 128 + dloc;
    const float bg = b_ig[down];
    const float wo = W_out[down];
    const float bo = b_out[0];
    const unsigned short* cip = ci + (size_t)row * L_ * D_ + down;

    // own-pair hp slot (uint index), swizzle slot(i)=((i>>3)<<3)|(((i&7)+(i>>3))&7)
    const int u_g = Q * 64 + w * 8 + r;
    const int i_w = u_g >> 2;
    const int wslot = ((((i_w >> 3) << 3) | (((i_w & 7) + (i_w >> 3)) & 7)) << 2) | (u_g & 3);

    unsigned int* myflag = flags + row * 16 + Q;
    unsigned int *pf0, *pf1, *pf2;
    {
        unsigned int* tmp[3]; int n = 0;
        for (int qq = 0; qq < NQ; ++qq) if (qq != Q) tmp[n++] = flags + row * 16 + qq;
        pf0 = tmp[0]; pf1 = tmp[1]; pf2 = tmp[2];
    }
    unsigned int fs0 = 0, fs1 = 0, fs2 = 0;   // cached last-seen partner flags

    float hval = 0.f;

    #pragma unroll 1
    for (int t = 0; t < L_; ++t) {
        unsigned short cu = cip[(size_t)t * D_];

        // commit out[t-1] (red[(t-1)&1] written pre-barrier(t-1); next
        // overwrite is at step t+1 after barrier(t) -> race-free window)
        if (tid == 0 && t > 0) {
            const float* rd = red[(t - 1) & 1];
            float s = rd[0] + rd[1] + rd[2] + rd[3] + rd[4] + rd[5] + rd[6] + rd[7];
            atomicAdd(out + row * L_ + (t - 1), s + (Q == 0 ? bo : 0.f));
        }

        uintx4 hsr[8];
        if (t == 0) {
            #pragma unroll
            for (int c = 0; c < 8; ++c) hsr[c] = (uintx4){0u, 0u, 0u, 0u};
        } else {
            // partners must have completed step t-1 (flag value >= t)
            unsigned int tt = (unsigned int)t;
            while (fs0 < tt) fs0 = __hip_atomic_load(pf0, __ATOMIC_RELAXED, __HIP_MEMORY_SCOPE_AGENT);
            while (fs1 < tt) fs1 = __hip_atomic_load(pf1, __ATOMIC_RELAXED, __HIP_MEMORY_SCOPE_AGENT);
            while (fs2 < tt) fs2 = __hip_atomic_load(pf2, __ATOMIC_RELAXED, __HIP_MEMORY_SCOPE_AGENT);
            if (own) {
                const uintx4* hrd = (const uintx4*)hp2[(t + 1) & 1];  // parity t-1
                #pragma unroll
                for (int c = 0; c < 8; ++c) hsr[c] = hrd[(g << 3) | ((c + g) & 7)];
            } else {
                // coherent (cross-XCD) reads from partner's posted half
                const uintx4* pb = (const uintx4*)(hbuf +
                    ((size_t)(((t - 1) & 1) * B_ + row) * NQ + pq) * 64 + (g & 1) * 32);
                asm volatile(
                    "global_load_dwordx4 %0, %8, off sc0 sc1\n\t"
                    "global_load_dwordx4 %1, %8, off offset:16 sc0 sc1\n\t"
                    "global_load_dwordx4 %2, %8, off offset:32 sc0 sc1\n\t"
                    "global_load_dwordx4 %3, %8, off offset:48 sc0 sc1\n\t"
                    "global_load_dwordx4 %4, %8, off offset:64 sc0 sc1\n\t"
                    "global_load_dwordx4 %5, %8, off offset:80 sc0 sc1\n\t"
                    "global_load_dwordx4 %6, %8, off offset:96 sc0 sc1\n\t"
                    "global_load_dwordx4 %7, %8, off offset:112 sc0 sc1\n\t"
                    "s_waitcnt vmcnt(0)"
                    : "=&v"(hsr[0]), "=&v"(hsr[1]), "=&v"(hsr[2]), "=&v"(hsr[3]),
                      "=&v"(hsr[4]), "=&v"(hsr[5]), "=&v"(hsr[6]), "=&v"(hsr[7])
                    : "v"(pb)
                    : "memory");
            }
        }

        float p0 = 0.f, p1 = 0.f;
        #pragma unroll
        for (int c = 0; c < 8; ++c) {
            p0 = dot4u(rr[c],     hsr[c], p0);
            p1 = dot4u(rr[8 + c], hsr[c], p1);
        }

        // 8-lane full reduce (xor7, xor1, xor2): every lane gets both sums
        float s0 = p0 + dpp_mov<0x141>(p0);
        float s1 = p1 + dpp_mov<0x141>(p1);
        s0 = s0 + dpp_mov<0xB1>(s0);
        s1 = s1 + dpp_mov<0xB1>(s1);
        s0 = s0 + dpp_mov<0x4E>(s0);
        s1 = s1 + dpp_mov<0x4E>(s1);
        float z = ((g & 1) ? s1 : s0) + bg;

        float ig  = __builtin_amdgcn_rcpf(1.f + __expf(-z));
        float civ = (float)__builtin_bit_cast(_Float16, cu);
        hval += civ * ig;

        // output partial: one copy per (group, j) -> lanes g<2 contribute
        float po = (g < 2) ? hval * wo : 0.f;
        po += dpp_mov<0xB1>(po);
        po += dpp_mov<0x4E>(po);
        po += dpp_mov<0x141>(po);
        po += dpp_mov<0x140>(po);
        po += dpp_mov<0x142>(po);
        po += dpp_mov<0x143>(po);
        if (l == 63) red[t & 1][w] = po;

        // pack pair (d even, d odd), publish own quarter to parity-t&1 bufs
        float nbh = dpp_mov<0xB1>(hval);
        if (g == 0) {
            unsigned int pair = __builtin_bit_cast(unsigned int,
                                  __builtin_amdgcn_cvt_pkrtz(hval, nbh));
            hp2[t & 1][wslot] = pair;
            unsigned int* dst = hbuf +
                ((size_t)((t & 1) * B_ + row) * NQ + Q) * 64 + (w * 8 + r);
            __hip_atomic_store(dst, pair, __ATOMIC_RELAXED, __HIP_MEMORY_SCOPE_AGENT);
        }

        __syncthreads();   // orders write(t) before read(t+1); drains vmcnt

        if (tid == 0)
            __hip_atomic_store(myflag, (unsigned int)(t + 1),
                               __ATOMIC_RELAXED, __HIP_MEMORY_SCOPE_AGENT);

        // early poll: seed next step's flag check to hide L3 latency
        if (t + 1 < L_) {
            fs0 = __hip_atomic_load(pf0, __ATOMIC_RELAXED, __HIP_MEMORY_SCOPE_AGENT);
            fs1 = __hip_atomic_load(pf1, __ATOMIC_RELAXED, __HIP_MEMORY_SCOPE_AGENT);
            fs2 = __hip_atomic_load(pf2, __ATOMIC_RELAXED, __HIP_MEMORY_SCOPE_AGENT);
        }
    }

    if (tid == 0) {
        const float* rd = red[(L_ - 1) & 1];
        float s = rd[0] + rd[1] + rd[2] + rd[3] + rd[4] + rd[5] + rd[6] + rd[7];
        atomicAdd(out + row * L_ + (L_ - 1), s + (Q == 0 ? bo : 0.f));
    }
}

extern "C" void kernel_launch(void* const* d_in, const int* in_sizes, int n_in,
                              void* d_out, int out_size, void* d_ws, size_t ws_size,
                              hipStream_t stream) {
    const float* obs   = (const float*)d_in[0];
    const float* act   = (const float*)d_in[1];
    const float* W_ci  = (const float*)d_in[2];
    const float* b_ci  = (const float*)d_in[3];
    const float* R_ig  = (const float*)d_in[4];
    const float* b_ig  = (const float*)d_in[5];
    const float* W_out = (const float*)d_in[6];
    const float* b_out = (const float*)d_in[7];
    float* out = (float*)d_out;

    unsigned short* ci  = (unsigned short*)d_ws;
    unsigned int* Rp    = (unsigned int*)((char*)d_ws + CI_BYTES);
    unsigned int* hbuf  = (unsigned int*)((char*)d_ws + CI_BYTES + RP_BYTES);
    unsigned int* flags = (unsigned int*)((char*)d_ws + CI_BYTES + RP_BYTES + HBUF_BYTES);

    prep_kernel<<<512, 256, 0, stream>>>(R_ig, Rp, flags, out);
    ci_kernel<<<(B_ * L_) / CI_R, 256, 0, stream>>>(obs, act, W_ci, b_ci, ci);
    scan_kernel<<<B_ * NQ, 512, 0, stream>>>(Rp, ci, b_ig, W_out, b_out, out, hbuf, flags);
}

// Round 5
// 823.295 us; speedup vs baseline: 1.8746x; 1.8746x over previous
//
#include <hip/hip_runtime.h>

// Custom LSTM scan.  B=64, L=512, P=64, A=16, D=512, F=80.
//   h_t = h_{t-1} + tanh(x_t W_ci + b_ci) * sigmoid(h_{t-1} R_ig + b_ig)
//
// R10 = R9 with the cvt_pkrtz typing fixed (builtin returns __fp16x2;
// bit_cast it directly, never assign to a _Float16x2 variable).
//
// R9 design: NQ=2 output split (128 WGs, 512 thr).  Per-thread R = 32
// uint4 = 128 regs -> R fully register-resident (V+A), zero per-step R
// memory traffic, no LDS-R (the DS pipe was the single-WG wall: 27
// b128/thr/step ~ 2600cy).  Cross-WG h exchange via self-tagged dwords
// (f16(h)<<16 | t+1): 256 fetcher threads each spin on ONE dword (4B,
// sc0 sc1, s_sleep-throttled, iteration-capped so a livelock becomes a
// finite fail, not a dead container), stage f16 into LDS, one lgkm-only
// barrier, then all lanes read h from LDS.  Per-step exchange traffic
// 1KB/WG (R8 was 64KB/WG -> suspected L3 congestion).  Tag freshness:
// same-parity tags never exceed t (partner's t+2 writes need all our t+1
// posts, which follow our barrier A(t), which follows all our tag-t
// fetches), so (tag==t) is exact.

#define B_  64
#define L_  512
#define P_  64
#define A_  16
#define D_  512
#define F_  80
#define CI_R 8

#define CI_BYTES   ((size_t)B_ * L_ * D_ * 2)        // 33,554,432
#define RP_BYTES   ((size_t)D_ * D_ * 2)             // 524,288
#define HBUF_UINTS (2 * B_ * 2 * 256)                // 65,536 (256 KB)
#define SPIN_CAP   16384

typedef _Float16 half2_t __attribute__((ext_vector_type(2)));
typedef unsigned int uintx4 __attribute__((ext_vector_type(4)));

__device__ __forceinline__ float dot2(unsigned int r, unsigned int h, float acc) {
    return __builtin_amdgcn_fdot2(__builtin_bit_cast(half2_t, h),
                                  __builtin_bit_cast(half2_t, r), acc, false);
}
__device__ __forceinline__ float dot4u(uintx4 r, uintx4 h, float acc) {
    acc = dot2(r.x, h.x, acc);
    acc = dot2(r.y, h.y, acc);
    acc = dot2(r.z, h.z, acc);
    acc = dot2(r.w, h.w, acc);
    return acc;
}
template<int CTRL>
__device__ __forceinline__ float dpp_mov(float v) {
    return __builtin_bit_cast(float, __builtin_amdgcn_update_dpp(
        0, __builtin_bit_cast(int, v), CTRL, 0xF, 0xF, true));
}
// DPP ctrls: 0xB1=xor1, 0x4E=xor2, 0x141=row_half_mirror(xor7),
// 0x140=row_mirror(xor15), 0x142=row_bcast15, 0x143=row_bcast31.

__device__ __forceinline__ unsigned int pk_f16(float a, float b) {
    return __builtin_bit_cast(unsigned int, __builtin_amdgcn_cvt_pkrtz(a, b));
}

// Pack R_ig fp32[k][d] -> f16-pair uint chunks, layout [q][m][tid_s][dw]:
// WG half q, thread tid_s (w=tid_s>>6, l=tid_s&63, r=l>>3, g=l&7),
// chunk m=j*8+c (j<4) holds pairs for output d = q*256 + (w*8+r)*4 + j at
// k0 = g*64 + c*8 + 2*dw.  Also zeroes hbuf (tags!) and out each launch.
__global__ __launch_bounds__(256) void prep_kernel(const float* __restrict__ R,
        unsigned int* __restrict__ Rp, unsigned int* __restrict__ hbuf,
        float* __restrict__ out) {
    int id = blockIdx.x * 256 + threadIdx.x;          // 131072 uints
    int dw = id & 3;
    int U = id >> 2;
    int tid_s = U & 511;
    int m  = (U >> 9) & 31;
    int qq = U >> 14;
    int w = tid_s >> 6, l = tid_s & 63, r = l >> 3, g = l & 7;
    int j = m >> 3, c = m & 7;
    int d  = qq * 256 + (w * 8 + r) * 4 + j;
    int k0 = g * 64 + c * 8 + 2 * dw;
    half2_t v;
    v.x = (_Float16)R[k0 * D_ + d];
    v.y = (_Float16)R[(k0 + 1) * D_ + d];
    Rp[id] = __builtin_bit_cast(unsigned int, v);
    if (id < HBUF_UINTS) hbuf[id] = 0u;
    if (id < B_ * L_) out[id] = 0.f;
}

// ci = tanh(x @ W_ci + b_ci), stored f16.  One block does CI_R (b,l) rows.
__global__ __launch_bounds__(256) void ci_kernel(const float* __restrict__ obs,
                                                 const float* __restrict__ act,
                                                 const float* __restrict__ W,
                                                 const float* __restrict__ bci,
                                                 unsigned short* __restrict__ ci) {
    __shared__ float xs[CI_R][F_];
    int row0 = blockIdx.x * CI_R;
    int tid = threadIdx.x;
    for (int idx = tid; idx < CI_R * F_; idx += 256) {
        int r = idx / F_, f = idx % F_;
        float v = (f < P_) ? obs[(size_t)(row0 + r) * P_ + f]
                           : act[(size_t)(row0 + r) * A_ + (f - P_)];
        xs[r][f] = v;
    }
    __syncthreads();
    int d0 = tid, d1 = tid + 256;
    float a0[CI_R], a1[CI_R];
    #pragma unroll
    for (int r = 0; r < CI_R; ++r) { a0[r] = 0.f; a1[r] = 0.f; }
    for (int f = 0; f < F_; ++f) {
        float w0 = W[f * D_ + d0];
        float w1 = W[f * D_ + d1];
        #pragma unroll
        for (int r = 0; r < CI_R; ++r) {
            float xv = xs[r][f];
            a0[r] += xv * w0;
            a1[r] += xv * w1;
        }
    }
    float b0 = bci[d0], b1 = bci[d1];
    #pragma unroll
    for (int r = 0; r < CI_R; ++r) {
        float z0 = a0[r] + b0, z1 = a1[r] + b1;
        float e0 = __expf(-2.f * __builtin_fabsf(z0));
        float e1 = __expf(-2.f * __builtin_fabsf(z1));
        float m0 = (1.f - e0) * __builtin_amdgcn_rcpf(1.f + e0);
        float m1 = (1.f - e1) * __builtin_amdgcn_rcpf(1.f + e1);
        float t0 = z0 < 0.f ? -m0 : m0;
        float t1 = z1 < 0.f ? -m1 : m1;
        ci[(size_t)(row0 + r) * D_ + d0] = __builtin_bit_cast(unsigned short, (_Float16)t0);
        ci[(size_t)(row0 + r) * D_ + d1] = __builtin_bit_cast(unsigned short, (_Float16)t1);
    }
}

// Serial scan, 2 WGs per batch row.  WG (row, q) owns d in [q*256,+256).
// Thread (w=tid>>6, l=tid&63, r=l>>3, g=l&7, g3=g&3): partials over
// k in [g*64,+64) for 4 outputs d = q*256 + (w*8+r)*4 + j, j=0..3;
// 8-lane DPP full-reduce, lane owns j=g3 (lanes g and g+4 duplicate).
// All 32 R chunks register-resident.  h source: own half (g>>2==q) from
// parity LDS hp2; remote half staged into LDS by 256 single-dword
// tag-spin fetchers, then read after a lgkmcnt-only barrier.
__global__ __launch_bounds__(512, 2)
__attribute__((amdgpu_waves_per_eu(2, 2)))
void scan_kernel(const unsigned int* __restrict__ Rp,
                 const unsigned short* __restrict__ ci,
                 const float* __restrict__ b_ig, const float* __restrict__ W_out,
                 const float* __restrict__ b_out, float* __restrict__ out,
                 unsigned int* __restrict__ hbuf)
{
    const int tid = threadIdx.x;
    const int bid = blockIdx.x;
    const int row = bid & 63;          // bid%8==row%8 -> row's 2 WGs same XCD (heuristic)
    const int q   = bid >> 6;
    const int w = tid >> 6;
    const int l = tid & 63;
    const int r = l >> 3;
    const int g = l & 7;
    const int g3 = g & 3;
    const bool own = ((g >> 2) == q);

    __shared__ __align__(16) unsigned int hp2[2][128];   // own-half h pairs, parity, swizzled
    __shared__ __align__(16) unsigned int hstage[128];   // remote-half h pairs, swizzled
    __shared__ float red[2][8];                          // po partials, parity

    // all 32 R chunks pinned in registers (128 regs, V and/or AGPR)
    const uintx4* tb = (const uintx4*)Rp + (size_t)q * 16384 + tid;
    uintx4 rr[32];
    #pragma unroll
    for (int m = 0; m < 32; ++m) rr[m] = tb[m * 512];
    #pragma unroll
    for (int m = 0; m < 32; ++m) asm volatile("" : "+v"(rr[m]));

    const int dloc = (w * 8 + r) * 4 + g3;
    const int down = q * 256 + dloc;
    const float bg = b_ig[down];
    const float wo = W_out[down];
    const float bo = b_out[0];
    const unsigned short* cip = ci + (size_t)row * L_ * D_ + down;

    // swizzle: logical uint4 lu -> phys uint4 (b<<3)|(((lu&7)+b)&7), b=lu>>3.
    // hp2 writer lanes g in {0,2}: pair u = (w*8+r)*2 + (g>>1)
    const int u_own = (w * 8 + r) * 2 + (g >> 1);
    const int lu_o = u_own >> 2, b_o = lu_o >> 3;
    const int wslot = (((b_o << 3) | (((lu_o & 7) + b_o) & 7)) << 2) | (u_own & 3);

    // fetcher (tid<256): spins on partner dword s=tid, stages short at:
    unsigned short* hstage_s = (unsigned short*)hstage;
    int phys_short = 0;
    {
        int s = tid & 255, u = s >> 1, lu = u >> 2, b = lu >> 3;
        int phys_u = (((b << 3) | (((lu & 7) + b) & 7)) << 2) | (u & 3);
        phys_short = phys_u * 2 + (s & 1);
    }

    float hval = 0.f;
    __syncthreads();

    #pragma unroll 1
    for (int t = 0; t < L_; ++t) {
        unsigned short cu = cip[(size_t)t * D_];   // issue early

        // commit out[t-1]: red[(t-1)&1] written post-A(t-1); next overwrite
        // is post-A(t+1) -> this read (pre-A(t)) is race-free
        if (tid == 0 && t > 0) {
            const float* rd = red[(t - 1) & 1];
            float s = rd[0] + rd[1] + rd[2] + rd[3] + rd[4] + rd[5] + rd[6] + rd[7];
            atomicAdd(out + row * L_ + (t - 1), s + (q == 0 ? bo : 0.f));
        }

        // fetch partner half: 1 tagged dword per fetcher thread
        if (t > 0 && tid < 256) {
            const unsigned int* src = hbuf +
                (((size_t)((t - 1) & 1) * B_ + row) * 2 + (1 - q)) * 256 + tid;
            const unsigned int tt = (unsigned int)t;
            unsigned int v;
            int it = 0;
            for (;;) {
                asm volatile("global_load_dword %0, %1, off sc0 sc1\n\t"
                             "s_waitcnt vmcnt(0)"
                             : "=v"(v) : "v"(src) : "memory");
                if ((v & 0xffffu) == tt) break;
                if (++it > SPIN_CAP) break;           // livelock -> finite fail
                __builtin_amdgcn_s_sleep(1);
            }
            hstage_s[phys_short] = (unsigned short)(v >> 16);
        }

        // barrier A: hstage visible (lgkm only; tagged stores stay in flight)
        if (t > 0) {
            asm volatile("s_waitcnt lgkmcnt(0)" ::: "memory");
            __builtin_amdgcn_s_barrier();
            asm volatile("" ::: "memory");
        }

        uintx4 hsr[8];
        if (t == 0) {
            #pragma unroll
            for (int c = 0; c < 8; ++c) hsr[c] = (uintx4){0u, 0u, 0u, 0u};
        } else {
            const uintx4* hrd = own ? (const uintx4*)hp2[(t + 1) & 1]   // parity t-1
                                    : (const uintx4*)hstage;
            #pragma unroll
            for (int c = 0; c < 8; ++c) hsr[c] = hrd[(g3 << 3) | ((c + g3) & 7)];
        }

        float p0 = 0.f, p1 = 0.f, p2 = 0.f, p3 = 0.f;
        #pragma unroll
        for (int c = 0; c < 8; ++c) {
            p0 = dot4u(rr[c],      hsr[c], p0);
            p1 = dot4u(rr[8 + c],  hsr[c], p1);
            p2 = dot4u(rr[16 + c], hsr[c], p2);
            p3 = dot4u(rr[24 + c], hsr[c], p3);
        }

        // 8-lane full reduce (xor7, xor1, xor2) per accumulator
        float s0 = p0 + dpp_mov<0x141>(p0);
        float s1 = p1 + dpp_mov<0x141>(p1);
        float s2 = p2 + dpp_mov<0x141>(p2);
        float s3 = p3 + dpp_mov<0x141>(p3);
        s0 = s0 + dpp_mov<0xB1>(s0);  s1 = s1 + dpp_mov<0xB1>(s1);
        s2 = s2 + dpp_mov<0xB1>(s2);  s3 = s3 + dpp_mov<0xB1>(s3);
        s0 = s0 + dpp_mov<0x4E>(s0);  s1 = s1 + dpp_mov<0x4E>(s1);
        s2 = s2 + dpp_mov<0x4E>(s2);  s3 = s3 + dpp_mov<0x4E>(s3);
        float z = ((g3 & 2) ? ((g3 & 1) ? s3 : s2)
                            : ((g3 & 1) ? s1 : s0)) + bg;

        float ig  = __builtin_amdgcn_rcpf(1.f + __expf(-z));
        float civ = (float)__builtin_bit_cast(_Float16, cu);
        hval += civ * ig;

        // output partial (lanes g<4 own distinct d; g>=4 duplicate -> 0)
        float po = (g < 4) ? hval * wo : 0.f;
        po += dpp_mov<0xB1>(po);
        po += dpp_mov<0x4E>(po);
        po += dpp_mov<0x141>(po);
        po += dpp_mov<0x140>(po);
        po += dpp_mov<0x142>(po);
        po += dpp_mov<0x143>(po);
        if (l == 63) red[t & 1][w] = po;

        // publish tagged h (g<4: one dword per owned d)
        if (g < 4) {
            unsigned int hb = pk_f16(hval, hval) & 0xffffu;
            unsigned int* dst = hbuf +
                (((size_t)(t & 1) * B_ + row) * 2 + q) * 256 + dloc;
            __hip_atomic_store(dst, (hb << 16) | (unsigned int)(t + 1),
                               __ATOMIC_RELAXED, __HIP_MEMORY_SCOPE_AGENT);
        }

        // publish own-half pair to LDS parity buffer (writers g in {0,2})
        float nbh = dpp_mov<0xB1>(hval);   // lane^1 = odd-d neighbor
        if (g == 0 || g == 2) {
            hp2[t & 1][wslot] = pk_f16(hval, nbh);
        }

        // barrier B: orders hp2/red writes vs next step (lgkm only)
        asm volatile("s_waitcnt lgkmcnt(0)" ::: "memory");
        __builtin_amdgcn_s_barrier();
        asm volatile("" ::: "memory");
    }

    if (tid == 0) {
        const float* rd = red[(L_ - 1) & 1];
        float s = rd[0] + rd[1] + rd[2] + rd[3] + rd[4] + rd[5] + rd[6] + rd[7];
        atomicAdd(out + row * L_ + (L_ - 1), s + (q == 0 ? bo : 0.f));
    }
}

extern "C" void kernel_launch(void* const* d_in, const int* in_sizes, int n_in,
                              void* d_out, int out_size, void* d_ws, size_t ws_size,
                              hipStream_t stream) {
    const float* obs   = (const float*)d_in[0];
    const float* act   = (const float*)d_in[1];
    const float* W_ci  = (const float*)d_in[2];
    const float* b_ci  = (const float*)d_in[3];
    const float* R_ig  = (const float*)d_in[4];
    const float* b_ig  = (const float*)d_in[5];
    const float* W_out = (const float*)d_in[6];
    const float* b_out = (const float*)d_in[7];
    float* out = (float*)d_out;

    unsigned short* ci  = (unsigned short*)d_ws;
    unsigned int* Rp    = (unsigned int*)((char*)d_ws + CI_BYTES);
    unsigned int* hbuf  = (unsigned int*)((char*)d_ws + CI_BYTES + RP_BYTES);

    prep_kernel<<<512, 256, 0, stream>>>(R_ig, Rp, hbuf, out);
    ci_kernel<<<(B_ * L_) / CI_R, 256, 0, stream>>>(obs, act, W_ci, b_ci, ci);
    scan_kernel<<<B_ * 2, 512, 0, stream>>>(Rp, ci, b_ig, W_out, b_out, out, hbuf);
}

// Round 7
// 673.685 us; speedup vs baseline: 2.2909x; 1.2221x over previous
//
#include <hip/hip_runtime.h>

// Custom LSTM scan.  B=64, L=512, P=64, A=16, D=512, F=80.
//   h_t = h_{t-1} + tanh(x_t W_ci + b_ci) * sigmoid(h_{t-1} R_ig + b_ig)
//
// R12: NQ=2 output split (128 WGs, 512 thr), R register-resident (32
// uint4/thread).  Exchange reverted to the PROVEN sc0sc1 (system-scope)
// tagged dwords of R10 -- R11's sc0-only "L2 path" was not CU-coherent
// (stale L1 spins -> SPIN_CAP breakout -> absmax 9.4).
// New vs R10: per-lane k-partition SPLIT ACROSS HALVES.  Lane g owns
// k in [hh*256 + (g&3)*64 + (g>>2)*32, +32) for BOTH hh=0,1.  Step:
//   issue tagged fetch (no wait) -> own-half dots (full occupancy,
//   overlaps the fetch RT and lets the partner's store age) ->
//   vmcnt(0)+tag check (usually first-try) -> stage to LDS -> barrier A
//   -> remote-half dots + 8-lane reduce + sigmoid + publish -> hp2/po/red
//   -> barrier B.
// R10 burned ~1500-2000cy/step spinning BEFORE any compute (store was
// 0cy old at first poll).  rr[] is loaded pre-swapped by q so all
// register-array indices are static (rule: runtime idx -> scratch).
// Single-bank LDS buffers (hazards proven against the 2-barrier
// schedule); rotation swizzle swz4 keeps h uint4 reads conflict-free.

#define B_  64
#define L_  512
#define P_  64
#define A_  16
#define D_  512
#define F_  80
#define CI_R 8

#define CI_BYTES   ((size_t)B_ * L_ * D_ * 2)        // 33,554,432
#define RP_BYTES   ((size_t)D_ * D_ * 2)             // 524,288
#define HBUF_UINTS (2 * B_ * 2 * 256)                // 65,536 (256 KB)
#define PBANK      ((size_t)B_ * 2 * 256)            // uints per parity bank
#define SPIN_CAP   65536

typedef _Float16 half2_t __attribute__((ext_vector_type(2)));
typedef unsigned int uintx4 __attribute__((ext_vector_type(4)));

__device__ __forceinline__ float dot2(unsigned int r, unsigned int h, float acc) {
    return __builtin_amdgcn_fdot2(__builtin_bit_cast(half2_t, h),
                                  __builtin_bit_cast(half2_t, r), acc, false);
}
__device__ __forceinline__ float dot4u(uintx4 r, uintx4 h, float acc) {
    acc = dot2(r.x, h.x, acc);
    acc = dot2(r.y, h.y, acc);
    acc = dot2(r.z, h.z, acc);
    acc = dot2(r.w, h.w, acc);
    return acc;
}
template<int CTRL>
__device__ __forceinline__ float dpp_mov(float v) {
    return __builtin_bit_cast(float, __builtin_amdgcn_update_dpp(
        0, __builtin_bit_cast(int, v), CTRL, 0xF, 0xF, true));
}
// DPP ctrls: 0xB1=xor1, 0x4E=xor2, 0x141=row_half_mirror(xor7),
// 0x140=row_mirror(xor15), 0x142=row_bcast15, 0x143=row_bcast31.

__device__ __forceinline__ unsigned int pk_f16(float a, float b) {
    return __builtin_bit_cast(unsigned int, __builtin_amdgcn_cvt_pkrtz(a, b));
}
__device__ __forceinline__ unsigned int ld_sc01(const unsigned int* p) {
    unsigned int v;
    asm volatile("global_load_dword %0, %1, off sc0 sc1\n\t"
                 "s_waitcnt vmcnt(0)" : "=v"(v) : "v"(p) : "memory");
    return v;
}
__device__ __forceinline__ void st_sc01(unsigned int* p, unsigned int v) {
    asm volatile("global_store_dword %0, %1, off sc0 sc1" :: "v"(p), "v"(v) : "memory");
}
// rotation swizzle over 32 uint4 slots: block b=i>>3 rotates by b
__device__ __forceinline__ int swz4(int i) {
    return ((i >> 3) << 3) | ((i + (i >> 3)) & 7);
}

// Pack R_ig fp32[k][d] -> f16-pair uint chunks, layout [q][m][tid_s][dw]:
// chunk m = hh*16 + j*4 + c of thread tid_s (w,l,r,g) in WG-half q holds
// pairs for output d = q*256 + (w*8+r)*4 + j at
// k0 = hh*256 + (g&3)*64 + (g>>2)*32 + c*8 + 2*dw.
// Also zeroes hbuf (tags!) and out each launch (graph-replay safe).
__global__ __launch_bounds__(256) void prep_kernel(const float* __restrict__ R,
        unsigned int* __restrict__ Rp, unsigned int* __restrict__ hbuf,
        float* __restrict__ out) {
    int id = blockIdx.x * 256 + threadIdx.x;          // 131072 uints
    int dw = id & 3;
    int U = id >> 2;
    int tid_s = U & 511;
    int m  = (U >> 9) & 31;
    int qq = U >> 14;
    int w = tid_s >> 6, l = tid_s & 63, r = l >> 3, g = l & 7;
    int hh = m >> 4, j = (m >> 2) & 3, c = m & 3;
    int d  = qq * 256 + (w * 8 + r) * 4 + j;
    int k0 = hh * 256 + (g & 3) * 64 + (g >> 2) * 32 + c * 8 + 2 * dw;
    half2_t v;
    v.x = (_Float16)R[k0 * D_ + d];
    v.y = (_Float16)R[(k0 + 1) * D_ + d];
    Rp[id] = __builtin_bit_cast(unsigned int, v);
    if (id < HBUF_UINTS) hbuf[id] = 0u;
    if (id < B_ * L_) out[id] = 0.f;
}

// ci = tanh(x @ W_ci + b_ci), stored f16.  One block does CI_R (b,l) rows.
__global__ __launch_bounds__(256) void ci_kernel(const float* __restrict__ obs,
                                                 const float* __restrict__ act,
                                                 const float* __restrict__ W,
                                                 const float* __restrict__ bci,
                                                 unsigned short* __restrict__ ci) {
    __shared__ float xs[CI_R][F_];
    int row0 = blockIdx.x * CI_R;
    int tid = threadIdx.x;
    for (int idx = tid; idx < CI_R * F_; idx += 256) {
        int r = idx / F_, f = idx % F_;
        float v = (f < P_) ? obs[(size_t)(row0 + r) * P_ + f]
                           : act[(size_t)(row0 + r) * A_ + (f - P_)];
        xs[r][f] = v;
    }
    __syncthreads();
    int d0 = tid, d1 = tid + 256;
    float a0[CI_R], a1[CI_R];
    #pragma unroll
    for (int r = 0; r < CI_R; ++r) { a0[r] = 0.f; a1[r] = 0.f; }
    for (int f = 0; f < F_; ++f) {
        float w0 = W[f * D_ + d0];
        float w1 = W[f * D_ + d1];
        #pragma unroll
        for (int r = 0; r < CI_R; ++r) {
            float xv = xs[r][f];
            a0[r] += xv * w0;
            a1[r] += xv * w1;
        }
    }
    float b0 = bci[d0], b1 = bci[d1];
    #pragma unroll
    for (int r = 0; r < CI_R; ++r) {
        float z0 = a0[r] + b0, z1 = a1[r] + b1;
        float e0 = __expf(-2.f * __builtin_fabsf(z0));
        float e1 = __expf(-2.f * __builtin_fabsf(z1));
        float m0 = (1.f - e0) * __builtin_amdgcn_rcpf(1.f + e0);
        float m1 = (1.f - e1) * __builtin_amdgcn_rcpf(1.f + e1);
        float t0 = z0 < 0.f ? -m0 : m0;
        float t1 = z1 < 0.f ? -m1 : m1;
        ci[(size_t)(row0 + r) * D_ + d0] = __builtin_bit_cast(unsigned short, (_Float16)t0);
        ci[(size_t)(row0 + r) * D_ + d1] = __builtin_bit_cast(unsigned short, (_Float16)t1);
    }
}

// Serial scan, 2 WGs per batch row.  WG (row,q) owns d in [q*256,+256).
// Thread (w,l,r,g): 4 outputs d = q*256+(w*8+r)*4+j; partials over
// k in [hh*256+(g&3)*64+(g>>2)*32, +32) for hh=q (phase2, from hp2) and
// hh=1-q (phase5, from hst).  8-lane DPP full reduce; lane owns j=g&3.
// rr[0..15]=own-half chunks, rr[16..31]=remote (pre-swapped by q).
__global__ __launch_bounds__(512, 2)
__attribute__((amdgpu_waves_per_eu(2, 2)))
void scan_kernel(const unsigned int* __restrict__ Rp,
                 const unsigned short* __restrict__ ci,
                 const float* __restrict__ b_ig, const float* __restrict__ W_out,
                 const float* __restrict__ b_out, float* __restrict__ out,
                 unsigned int* __restrict__ hbuf)
{
    const int tid = threadIdx.x;
    const int bid = blockIdx.x;
    const int row = bid & 63;
    const int q   = bid >> 6;
    const int w = tid >> 6;
    const int l = tid & 63;
    const int r = l >> 3;
    const int g = l & 7;
    const int g3 = g & 3;

    __shared__ __align__(16) unsigned int hp2[128];   // own-half h pairs, swizzled
    __shared__ __align__(16) unsigned int hst[128];   // remote-half h pairs, swizzled
    __shared__ float red[8];                          // po partials

    // rr pre-swapped: rr[mm] = chunk (mm ^ (q<<4)) -> rr[0..15] own half
    const uintx4* tb = (const uintx4*)Rp + (size_t)q * 16384 + tid;
    const int qx = q << 4;
    uintx4 rr[32];
    #pragma unroll
    for (int mm = 0; mm < 32; ++mm) rr[mm] = tb[(mm ^ qx) * 512];
    #pragma unroll
    for (int mm = 0; mm < 32; ++mm) asm volatile("" : "+v"(rr[mm]));

    const int dloc = (w * 8 + r) * 4 + g3;
    const int down = q * 256 + dloc;
    const float bg = b_ig[down];
    const float wo = W_out[down];
    const float bo = b_out[0];
    const unsigned short* cip = ci + (size_t)row * L_ * D_ + down;

    // hp2 writer slot (lanes g in {0,2}): pair u = (w*8+r)*2 + (g>>1)
    const int u_own = (w * 8 + r) * 2 + (g >> 1);
    const int wslot = swz4(u_own >> 2) * 4 + (u_own & 3);
    // hst fetcher slot: s=tid<256, pair u=s>>1, even lanes write packed dword
    const int s_f = tid & 255;
    const int stslot = swz4(s_f >> 3) * 4 + ((s_f >> 1) & 3);
    // h-read uint4 base index: i = (g&3)*8 + (g>>2)*4 + c
    const int ib = (g & 3) * 8 + (g >> 2) * 4;
    const int ri0 = swz4(ib + 0), ri1 = swz4(ib + 1);
    const int ri2 = swz4(ib + 2), ri3 = swz4(ib + 3);

    const unsigned int* rdbase = hbuf + ((size_t)row * 2 + (1 - q)) * 256 + s_f;
    unsigned int* wrbase = hbuf + ((size_t)row * 2 + q) * 256 + dloc;

    float hval = 0.f;
    __syncthreads();

    #pragma unroll 1
    for (int t = 0; t < L_; ++t) {
        unsigned short cu = cip[(size_t)t * D_];   // issue early

        // issue tagged fetch (no wait) -- RT overlaps own-half dots
        unsigned int vfetch = 0;
        const unsigned int* src = rdbase + (size_t)((t - 1) & 1) * PBANK;
        if (t > 0 && tid < 256) {
            asm volatile("global_load_dword %0, %1, off sc0 sc1"
                         : "=&v"(vfetch) : "v"(src) : "memory");
        }

        // commit out[t-1]: red written pre-B(t-1); overwritten post-A(t)
        if (tid == 0 && t > 0) {
            float s = red[0] + red[1] + red[2] + red[3] +
                      red[4] + red[5] + red[6] + red[7];
            atomicAdd(out + row * L_ + (t - 1), s + (q == 0 ? bo : 0.f));
        }

        float p0 = 0.f, p1 = 0.f, p2 = 0.f, p3 = 0.f;

        // phase2: own-half dots from hp2 (written at t-1 behind B(t-1))
        if (t > 0) {
            const uintx4* hp4 = (const uintx4*)hp2;
            uintx4 h0 = hp4[ri0], h1 = hp4[ri1], h2 = hp4[ri2], h3 = hp4[ri3];
            p0 = dot4u(rr[0],  h0, p0); p0 = dot4u(rr[1],  h1, p0);
            p0 = dot4u(rr[2],  h2, p0); p0 = dot4u(rr[3],  h3, p0);
            p1 = dot4u(rr[4],  h0, p1); p1 = dot4u(rr[5],  h1, p1);
            p1 = dot4u(rr[6],  h2, p1); p1 = dot4u(rr[7],  h3, p1);
            p2 = dot4u(rr[8],  h0, p2); p2 = dot4u(rr[9],  h1, p2);
            p2 = dot4u(rr[10], h2, p2); p2 = dot4u(rr[11], h3, p2);
            p3 = dot4u(rr[12], h0, p3); p3 = dot4u(rr[13], h1, p3);
            p3 = dot4u(rr[14], h2, p3); p3 = dot4u(rr[15], h3, p3);
        }

        // phase3: complete fetch, tag-check (rarely spins now), stage to LDS
        if (t > 0 && tid < 256) {
            asm volatile("s_waitcnt vmcnt(0)" : "+v"(vfetch) :: "memory");
            const unsigned int tt = (unsigned int)t;
            int it = 0;
            while ((vfetch & 0xffffu) != tt) {
                if (++it > SPIN_CAP) break;            // finite fail, no hang
                if (it > 2) __builtin_amdgcn_s_sleep(1);
                vfetch = ld_sc01(src);
            }
            unsigned int vo = __builtin_bit_cast(unsigned int,
                                dpp_mov<0xB1>(__builtin_bit_cast(float, vfetch)));
            if ((tid & 1) == 0)
                hst[stslot] = (vfetch >> 16) | (vo & 0xffff0000u);
        }

        // barrier A: hst visible; also separates phase2 reads from hp2 rewrite
        asm volatile("s_waitcnt lgkmcnt(0)" ::: "memory");
        __builtin_amdgcn_s_barrier();
        asm volatile("" ::: "memory");

        // phase5: remote-half dots from hst
        if (t > 0) {
            const uintx4* hs4 = (const uintx4*)hst;
            uintx4 h0 = hs4[ri0], h1 = hs4[ri1], h2 = hs4[ri2], h3 = hs4[ri3];
            p0 = dot4u(rr[16], h0, p0); p0 = dot4u(rr[17], h1, p0);
            p0 = dot4u(rr[18], h2, p0); p0 = dot4u(rr[19], h3, p0);
            p1 = dot4u(rr[20], h0, p1); p1 = dot4u(rr[21], h1, p1);
            p1 = dot4u(rr[22], h2, p1); p1 = dot4u(rr[23], h3, p1);
            p2 = dot4u(rr[24], h0, p2); p2 = dot4u(rr[25], h1, p2);
            p2 = dot4u(rr[26], h2, p2); p2 = dot4u(rr[27], h3, p2);
            p3 = dot4u(rr[28], h0, p3); p3 = dot4u(rr[29], h1, p3);
            p3 = dot4u(rr[30], h2, p3); p3 = dot4u(rr[31], h3, p3);
        }

        // 8-lane full reduce (xor7, xor1, xor2) per accumulator
        float s0 = p0 + dpp_mov<0x141>(p0);
        float s1 = p1 + dpp_mov<0x141>(p1);
        float s2 = p2 + dpp_mov<0x141>(p2);
        float s3 = p3 + dpp_mov<0x141>(p3);
        s0 = s0 + dpp_mov<0xB1>(s0);  s1 = s1 + dpp_mov<0xB1>(s1);
        s2 = s2 + dpp_mov<0xB1>(s2);  s3 = s3 + dpp_mov<0xB1>(s3);
        s0 = s0 + dpp_mov<0x4E>(s0);  s1 = s1 + dpp_mov<0x4E>(s1);
        s2 = s2 + dpp_mov<0x4E>(s2);  s3 = s3 + dpp_mov<0x4E>(s3);
        float z = ((g3 & 2) ? ((g3 & 1) ? s3 : s2)
                            : ((g3 & 1) ? s1 : s0)) + bg;

        float ig  = __builtin_amdgcn_rcpf(1.f + __expf(-z));
        float civ = (float)__builtin_bit_cast(_Float16, cu);
        hval += civ * ig;

        // publish tagged h ASAP (g<4: each owned d exactly once)
        if (g < 4) {
            unsigned int hb = pk_f16(hval, hval) & 0xffffu;
            st_sc01(wrbase + (size_t)(t & 1) * PBANK,
                    (hb << 16) | (unsigned int)(t + 1));
        }

        // output partial (g<4 distinct d; g>=4 duplicates -> 0)
        float po = (g < 4) ? hval * wo : 0.f;
        po += dpp_mov<0xB1>(po);
        po += dpp_mov<0x4E>(po);
        po += dpp_mov<0x141>(po);
        po += dpp_mov<0x140>(po);
        po += dpp_mov<0x142>(po);
        po += dpp_mov<0x143>(po);
        if (l == 63) red[w] = po;

        // own-half pair publish to hp2 (writers g in {0,2})
        float nbh = dpp_mov<0xB1>(hval);   // lane^1 = odd-d neighbor
        if (g == 0 || g == 2) {
            hp2[wslot] = pk_f16(hval, nbh);
        }

        // barrier B: hp2/red writes ordered before next step's reads
        asm volatile("s_waitcnt lgkmcnt(0)" ::: "memory");
        __builtin_amdgcn_s_barrier();
        asm volatile("" ::: "memory");
    }

    if (tid == 0) {
        float s = red[0] + red[1] + red[2] + red[3] +
                  red[4] + red[5] + red[6] + red[7];
        atomicAdd(out + row * L_ + (L_ - 1), s + (q == 0 ? bo : 0.f));
    }
}

extern "C" void kernel_launch(void* const* d_in, const int* in_sizes, int n_in,
                              void* d_out, int out_size, void* d_ws, size_t ws_size,
                              hipStream_t stream) {
    const float* obs   = (const float*)d_in[0];
    const float* act   = (const float*)d_in[1];
    const float* W_ci  = (const float*)d_in[2];
    const float* b_ci  = (const float*)d_in[3];
    const float* R_ig  = (const float*)d_in[4];
    const float* b_ig  = (const float*)d_in[5];
    const float* W_out = (const float*)d_in[6];
    const float* b_out = (const float*)d_in[7];
    float* out = (float*)d_out;

    unsigned short* ci = (unsigned short*)d_ws;
    unsigned int* Rp   = (unsigned int*)((char*)d_ws + CI_BYTES);
    unsigned int* hbuf = (unsigned int*)((char*)d_ws + CI_BYTES + RP_BYTES);

    prep_kernel<<<512, 256, 0, stream>>>(R_ig, Rp, hbuf, out);
    ci_kernel<<<(B_ * L_) / CI_R, 256, 0, stream>>>(obs, act, W_ci, b_ci, ci);
    scan_kernel<<<B_ * 2, 512, 0, stream>>>(Rp, ci, b_ig, W_out, b_out, out, hbuf);
}

// Round 8
// 618.672 us; speedup vs baseline: 2.4946x; 1.0889x over previous
//
#include <hip/hip_runtime.h>

// Custom LSTM scan.  B=64, L=512, P=64, A=16, D=512, F=80.
//   h_t = h_{t-1} + tanh(x_t W_ci + b_ci) * sigmoid(h_{t-1} R_ig + b_ig)
//
// R13 = R12 + three critical-chain changes (R12 measured: 2650cy/step;
// lockstep WGs mean the partner's sc0sc1 store is ~100cy old at first
// poll while LLC visibility is ~600-900cy -> every step paid 1-2 SERIAL
// retry round trips):
//  1) BATCHED PIPELINED POLL: 3 loads to the same tagged dword spaced by
//     s_sleep(1), checked oldest-first via vmcnt(2/1/0).  One batch
//     samples 3 time points in ~one RT instead of 3 serial RTs.
//  2) EARLIER PUBLISH / SHORTER TAIL: hval -> tagged publish -> hp2
//     write -> barrier B.  po-reduce moved AFTER barrier B.
//  3) red[] + tid0 commit replaced by per-wave lane63 atomicAdd of the
//     wave partial into out[row*L+t] (fire-and-forget, off-chain; bo
//     added by wave0 of q0).  prep zeroes out每 launch -> replay-safe.
// Everything else (NQ=2 split, register-resident R, split-k own/remote
// partition, swizzled LDS h buffers, sc0sc1 tagged exchange) is R12,
// which passed at absmax 0.125.

#define B_  64
#define L_  512
#define P_  64
#define A_  16
#define D_  512
#define F_  80
#define CI_R 8

#define CI_BYTES   ((size_t)B_ * L_ * D_ * 2)        // 33,554,432
#define RP_BYTES   ((size_t)D_ * D_ * 2)             // 524,288
#define HBUF_UINTS (2 * B_ * 2 * 256)                // 65,536 (256 KB)
#define PBANK      ((size_t)B_ * 2 * 256)            // uints per parity bank
#define BATCH_CAP  4096

typedef _Float16 half2_t __attribute__((ext_vector_type(2)));
typedef unsigned int uintx4 __attribute__((ext_vector_type(4)));

__device__ __forceinline__ float dot2(unsigned int r, unsigned int h, float acc) {
    return __builtin_amdgcn_fdot2(__builtin_bit_cast(half2_t, h),
                                  __builtin_bit_cast(half2_t, r), acc, false);
}
__device__ __forceinline__ float dot4u(uintx4 r, uintx4 h, float acc) {
    acc = dot2(r.x, h.x, acc);
    acc = dot2(r.y, h.y, acc);
    acc = dot2(r.z, h.z, acc);
    acc = dot2(r.w, h.w, acc);
    return acc;
}
template<int CTRL>
__device__ __forceinline__ float dpp_mov(float v) {
    return __builtin_bit_cast(float, __builtin_amdgcn_update_dpp(
        0, __builtin_bit_cast(int, v), CTRL, 0xF, 0xF, true));
}
// DPP ctrls: 0xB1=xor1, 0x4E=xor2, 0x141=row_half_mirror(xor7),
// 0x140=row_mirror(xor15), 0x142=row_bcast15, 0x143=row_bcast31.

__device__ __forceinline__ unsigned int pk_f16(float a, float b) {
    return __builtin_bit_cast(unsigned int, __builtin_amdgcn_cvt_pkrtz(a, b));
}
__device__ __forceinline__ void st_sc01(unsigned int* p, unsigned int v) {
    asm volatile("global_store_dword %0, %1, off sc0 sc1" :: "v"(p), "v"(v) : "memory");
}
// rotation swizzle over 32 uint4 slots: block b=i>>3 rotates by b
__device__ __forceinline__ int swz4(int i) {
    return ((i >> 3) << 3) | ((i + (i >> 3)) & 7);
}

// Pack R_ig fp32[k][d] -> f16-pair uint chunks, layout [q][m][tid_s][dw]:
// chunk m = hh*16 + j*4 + c of thread tid_s (w,l,r,g) in WG-half q holds
// pairs for output d = q*256 + (w*8+r)*4 + j at
// k0 = hh*256 + (g&3)*64 + (g>>2)*32 + c*8 + 2*dw.
// Also zeroes hbuf (tags!) and out each launch (graph-replay safe).
__global__ __launch_bounds__(256) void prep_kernel(const float* __restrict__ R,
        unsigned int* __restrict__ Rp, unsigned int* __restrict__ hbuf,
        float* __restrict__ out) {
    int id = blockIdx.x * 256 + threadIdx.x;          // 131072 uints
    int dw = id & 3;
    int U = id >> 2;
    int tid_s = U & 511;
    int m  = (U >> 9) & 31;
    int qq = U >> 14;
    int w = tid_s >> 6, l = tid_s & 63, r = l >> 3, g = l & 7;
    int hh = m >> 4, j = (m >> 2) & 3, c = m & 3;
    int d  = qq * 256 + (w * 8 + r) * 4 + j;
    int k0 = hh * 256 + (g & 3) * 64 + (g >> 2) * 32 + c * 8 + 2 * dw;
    half2_t v;
    v.x = (_Float16)R[k0 * D_ + d];
    v.y = (_Float16)R[(k0 + 1) * D_ + d];
    Rp[id] = __builtin_bit_cast(unsigned int, v);
    if (id < HBUF_UINTS) hbuf[id] = 0u;
    if (id < B_ * L_) out[id] = 0.f;
}

// ci = tanh(x @ W_ci + b_ci), stored f16.  One block does CI_R (b,l) rows.
__global__ __launch_bounds__(256) void ci_kernel(const float* __restrict__ obs,
                                                 const float* __restrict__ act,
                                                 const float* __restrict__ W,
                                                 const float* __restrict__ bci,
                                                 unsigned short* __restrict__ ci) {
    __shared__ float xs[CI_R][F_];
    int row0 = blockIdx.x * CI_R;
    int tid = threadIdx.x;
    for (int idx = tid; idx < CI_R * F_; idx += 256) {
        int r = idx / F_, f = idx % F_;
        float v = (f < P_) ? obs[(size_t)(row0 + r) * P_ + f]
                           : act[(size_t)(row0 + r) * A_ + (f - P_)];
        xs[r][f] = v;
    }
    __syncthreads();
    int d0 = tid, d1 = tid + 256;
    float a0[CI_R], a1[CI_R];
    #pragma unroll
    for (int r = 0; r < CI_R; ++r) { a0[r] = 0.f; a1[r] = 0.f; }
    for (int f = 0; f < F_; ++f) {
        float w0 = W[f * D_ + d0];
        float w1 = W[f * D_ + d1];
        #pragma unroll
        for (int r = 0; r < CI_R; ++r) {
            float xv = xs[r][f];
            a0[r] += xv * w0;
            a1[r] += xv * w1;
        }
    }
    float b0 = bci[d0], b1 = bci[d1];
    #pragma unroll
    for (int r = 0; r < CI_R; ++r) {
        float z0 = a0[r] + b0, z1 = a1[r] + b1;
        float e0 = __expf(-2.f * __builtin_fabsf(z0));
        float e1 = __expf(-2.f * __builtin_fabsf(z1));
        float m0 = (1.f - e0) * __builtin_amdgcn_rcpf(1.f + e0);
        float m1 = (1.f - e1) * __builtin_amdgcn_rcpf(1.f + e1);
        float t0 = z0 < 0.f ? -m0 : m0;
        float t1 = z1 < 0.f ? -m1 : m1;
        ci[(size_t)(row0 + r) * D_ + d0] = __builtin_bit_cast(unsigned short, (_Float16)t0);
        ci[(size_t)(row0 + r) * D_ + d1] = __builtin_bit_cast(unsigned short, (_Float16)t1);
    }
}

// Serial scan, 2 WGs per batch row.  WG (row,q) owns d in [q*256,+256).
// Thread (w,l,r,g): 4 outputs d = q*256+(w*8+r)*4+j; partials over
// k in [hh*256+(g&3)*64+(g>>2)*32, +32) for hh=q (phase2, hp2) and
// hh=1-q (phase5, hst).  8-lane DPP full reduce; lane owns j=g&3.
// rr[0..15]=own-half chunks, rr[16..31]=remote (pre-swapped by q).
__global__ __launch_bounds__(512, 2)
__attribute__((amdgpu_waves_per_eu(2, 2)))
void scan_kernel(const unsigned int* __restrict__ Rp,
                 const unsigned short* __restrict__ ci,
                 const float* __restrict__ b_ig, const float* __restrict__ W_out,
                 const float* __restrict__ b_out, float* __restrict__ out,
                 unsigned int* __restrict__ hbuf)
{
    const int tid = threadIdx.x;
    const int bid = blockIdx.x;
    const int row = bid & 63;
    const int q   = bid >> 6;
    const int w = tid >> 6;
    const int l = tid & 63;
    const int r = l >> 3;
    const int g = l & 7;
    const int g3 = g & 3;

    __shared__ __align__(16) unsigned int hp2[128];   // own-half h pairs, swizzled
    __shared__ __align__(16) unsigned int hst[128];   // remote-half h pairs, swizzled

    // rr pre-swapped: rr[mm] = chunk (mm ^ (q<<4)) -> rr[0..15] own half
    const uintx4* tb = (const uintx4*)Rp + (size_t)q * 16384 + tid;
    const int qx = q << 4;
    uintx4 rr[32];
    #pragma unroll
    for (int mm = 0; mm < 32; ++mm) rr[mm] = tb[(mm ^ qx) * 512];
    #pragma unroll
    for (int mm = 0; mm < 32; ++mm) asm volatile("" : "+v"(rr[mm]));

    const int dloc = (w * 8 + r) * 4 + g3;
    const int down = q * 256 + dloc;
    const float bg = b_ig[down];
    const float wo = W_out[down];
    const float bo = b_out[0];
    const unsigned short* cip = ci + (size_t)row * L_ * D_ + down;

    // hp2 writer slot (lanes g in {0,2}): pair u = (w*8+r)*2 + (g>>1)
    const int u_own = (w * 8 + r) * 2 + (g >> 1);
    const int wslot = swz4(u_own >> 2) * 4 + (u_own & 3);
    // hst fetcher slot: s=tid<256, pair u=s>>1, even lanes write packed dword
    const int s_f = tid & 255;
    const int stslot = swz4(s_f >> 3) * 4 + ((s_f >> 1) & 3);
    // h-read uint4 base index: i = (g&3)*8 + (g>>2)*4 + c
    const int ib = (g & 3) * 8 + (g >> 2) * 4;
    const int ri0 = swz4(ib + 0), ri1 = swz4(ib + 1);
    const int ri2 = swz4(ib + 2), ri3 = swz4(ib + 3);

    const unsigned int* rdbase = hbuf + ((size_t)row * 2 + (1 - q)) * 256 + s_f;
    unsigned int* wrbase = hbuf + ((size_t)row * 2 + q) * 256 + dloc;

    float hval = 0.f;
    __syncthreads();

    #pragma unroll 1
    for (int t = 0; t < L_; ++t) {
        unsigned short cu = cip[(size_t)t * D_];   // issue early

        // issue tagged fetch (no wait) -- RT overlaps own-half dots
        unsigned int vfetch = 0;
        const unsigned int* src = rdbase + (size_t)((t - 1) & 1) * PBANK;
        if (t > 0 && tid < 256) {
            asm volatile("global_load_dword %0, %1, off sc0 sc1"
                         : "=&v"(vfetch) : "v"(src) : "memory");
        }

        float p0 = 0.f, p1 = 0.f, p2 = 0.f, p3 = 0.f;

        // phase2: own-half dots from hp2 (written at tail(t-1), behind B)
        if (t > 0) {
            const uintx4* hp4 = (const uintx4*)hp2;
            uintx4 h0 = hp4[ri0], h1 = hp4[ri1], h2 = hp4[ri2], h3 = hp4[ri3];
            p0 = dot4u(rr[0],  h0, p0); p0 = dot4u(rr[1],  h1, p0);
            p0 = dot4u(rr[2],  h2, p0); p0 = dot4u(rr[3],  h3, p0);
            p1 = dot4u(rr[4],  h0, p1); p1 = dot4u(rr[5],  h1, p1);
            p1 = dot4u(rr[6],  h2, p1); p1 = dot4u(rr[7],  h3, p1);
            p2 = dot4u(rr[8],  h0, p2); p2 = dot4u(rr[9],  h1, p2);
            p2 = dot4u(rr[10], h2, p2); p2 = dot4u(rr[11], h3, p2);
            p3 = dot4u(rr[12], h0, p3); p3 = dot4u(rr[13], h1, p3);
            p3 = dot4u(rr[14], h2, p3); p3 = dot4u(rr[15], h3, p3);
        }

        // phase3: finish fetch; if stale, batched pipelined poll (3 loads
        // spaced by s_sleep, checked oldest-first via vmcnt(2/1/0) -- one
        // RT per 3 samples instead of 3 serial RTs).  Stage into hst.
        if (t > 0 && tid < 256) {
            asm volatile("s_waitcnt vmcnt(0)" : "+v"(vfetch) :: "memory");
            const unsigned int tt = (unsigned int)t;
            if ((vfetch & 0xffffu) != tt) {
                int it = 0;
                unsigned int a0, a1, a2;
                for (;;) {
                    asm volatile("global_load_dword %0, %1, off sc0 sc1"
                                 : "=&v"(a0) : "v"(src) : "memory");
                    __builtin_amdgcn_s_sleep(1);
                    asm volatile("global_load_dword %0, %1, off sc0 sc1"
                                 : "=&v"(a1) : "v"(src) : "memory");
                    __builtin_amdgcn_s_sleep(1);
                    asm volatile("global_load_dword %0, %1, off sc0 sc1"
                                 : "=&v"(a2) : "v"(src) : "memory");
                    asm volatile("s_waitcnt vmcnt(2)" ::: "memory");
                    if ((a0 & 0xffffu) == tt) {
                        vfetch = a0;
                        asm volatile("s_waitcnt vmcnt(0)" ::: "memory");
                        break;
                    }
                    asm volatile("s_waitcnt vmcnt(1)" ::: "memory");
                    if ((a1 & 0xffffu) == tt) {
                        vfetch = a1;
                        asm volatile("s_waitcnt vmcnt(0)" ::: "memory");
                        break;
                    }
                    asm volatile("s_waitcnt vmcnt(0)" ::: "memory");
                    if ((a2 & 0xffffu) == tt) { vfetch = a2; break; }
                    if (++it > BATCH_CAP) break;       // finite fail, no hang
                    __builtin_amdgcn_s_sleep(1);
                }
            }
            unsigned int vo = __builtin_bit_cast(unsigned int,
                                dpp_mov<0xB1>(__builtin_bit_cast(float, vfetch)));
            if ((tid & 1) == 0)
                hst[stslot] = (vfetch >> 16) | (vo & 0xffff0000u);
        }

        // barrier A: hst visible; separates phase2 reads from hp2 rewrite
        asm volatile("s_waitcnt lgkmcnt(0)" ::: "memory");
        __builtin_amdgcn_s_barrier();
        asm volatile("" ::: "memory");

        // phase5: remote-half dots from hst
        if (t > 0) {
            const uintx4* hs4 = (const uintx4*)hst;
            uintx4 h0 = hs4[ri0], h1 = hs4[ri1], h2 = hs4[ri2], h3 = hs4[ri3];
            p0 = dot4u(rr[16], h0, p0); p0 = dot4u(rr[17], h1, p0);
            p0 = dot4u(rr[18], h2, p0); p0 = dot4u(rr[19], h3, p0);
            p1 = dot4u(rr[20], h0, p1); p1 = dot4u(rr[21], h1, p1);
            p1 = dot4u(rr[22], h2, p1); p1 = dot4u(rr[23], h3, p1);
            p2 = dot4u(rr[24], h0, p2); p2 = dot4u(rr[25], h1, p2);
            p2 = dot4u(rr[26], h2, p2); p2 = dot4u(rr[27], h3, p2);
            p3 = dot4u(rr[28], h0, p3); p3 = dot4u(rr[29], h1, p3);
            p3 = dot4u(rr[30], h2, p3); p3 = dot4u(rr[31], h3, p3);
        }

        // 8-lane full reduce (xor7, xor1, xor2) per accumulator
        float s0 = p0 + dpp_mov<0x141>(p0);
        float s1 = p1 + dpp_mov<0x141>(p1);
        float s2 = p2 + dpp_mov<0x141>(p2);
        float s3 = p3 + dpp_mov<0x141>(p3);
        s0 = s0 + dpp_mov<0xB1>(s0);  s1 = s1 + dpp_mov<0xB1>(s1);
        s2 = s2 + dpp_mov<0xB1>(s2);  s3 = s3 + dpp_mov<0xB1>(s3);
        s0 = s0 + dpp_mov<0x4E>(s0);  s1 = s1 + dpp_mov<0x4E>(s1);
        s2 = s2 + dpp_mov<0x4E>(s2);  s3 = s3 + dpp_mov<0x4E>(s3);
        float z = ((g3 & 2) ? ((g3 & 1) ? s3 : s2)
                            : ((g3 & 1) ? s1 : s0)) + bg;

        float ig  = __builtin_amdgcn_rcpf(1.f + __expf(-z));
        float civ = (float)__builtin_bit_cast(_Float16, cu);
        hval += civ * ig;

        // publish tagged h IMMEDIATELY (g<4: each owned d exactly once) --
        // this starts the partner's visibility clock
        if (g < 4) {
            unsigned int hb = pk_f16(hval, hval) & 0xffffu;
            st_sc01(wrbase + (size_t)(t & 1) * PBANK,
                    (hb << 16) | (unsigned int)(t + 1));
        }

        // own-half pair publish to hp2 (writers g in {0,2})
        float nbh = dpp_mov<0xB1>(hval);   // lane^1 = odd-d neighbor
        if (g == 0 || g == 2) {
            hp2[wslot] = pk_f16(hval, nbh);
        }

        // barrier B: hp2 writes ordered before next step's phase2 reads
        asm volatile("s_waitcnt lgkmcnt(0)" ::: "memory");
        __builtin_amdgcn_s_barrier();
        asm volatile("" ::: "memory");

        // out[t] commit, post-B (off the critical chain): per-wave
        // full-64-lane reduce of hval*wo (g<4 lanes hold distinct d),
        // lane 63 atomicAdds the wave partial; wave0 of q0 adds bo.
        float po = (g < 4) ? hval * wo : 0.f;
        po += dpp_mov<0xB1>(po);
        po += dpp_mov<0x4E>(po);
        po += dpp_mov<0x141>(po);
        po += dpp_mov<0x140>(po);
        po += dpp_mov<0x142>(po);
        po += dpp_mov<0x143>(po);
        if (l == 63) {
            float addv = po + ((q == 0 && w == 0) ? bo : 0.f);
            atomicAdd(out + row * L_ + t, addv);
        }
    }
}

extern "C" void kernel_launch(void* const* d_in, const int* in_sizes, int n_in,
                              void* d_out, int out_size, void* d_ws, size_t ws_size,
                              hipStream_t stream) {
    const float* obs   = (const float*)d_in[0];
    const float* act   = (const float*)d_in[1];
    const float* W_ci  = (const float*)d_in[2];
    const float* b_ci  = (const float*)d_in[3];
    const float* R_ig  = (const float*)d_in[4];
    const float* b_ig  = (const float*)d_in[5];
    const float* W_out = (const float*)d_in[6];
    const float* b_out = (const float*)d_in[7];
    float* out = (float*)d_out;

    unsigned short* ci = (unsigned short*)d_ws;
    unsigned int* Rp   = (unsigned int*)((char*)d_ws + CI_BYTES);
    unsigned int* hbuf = (unsigned int*)((char*)d_ws + CI_BYTES + RP_BYTES);

    prep_kernel<<<512, 256, 0, stream>>>(R_ig, Rp, hbuf, out);
    ci_kernel<<<(B_ * L_) / CI_R, 256, 0, stream>>>(obs, act, W_ci, b_ci, ci);
    scan_kernel<<<B_ * 2, 512, 0, stream>>>(Rp, ci, b_ig, W_out, b_out, out, hbuf);
}